// Round 5
// baseline (119.608 us; speedup 1.0000x reference)
//
#include <hip/hip_runtime.h>
#include <cmath>
#include <cfloat>

// Problem constants (fixed by setup_inputs: B=4, Q=100, K=17, H=W=128).
constexpr int NB = 4;
constexpr int NQ = 100;
constexpr int NK = 17;
constexpr int NH = 128;
constexpr int NW = 128;

constexpr float HUMAN_CONF = 0.7f;
constexpr float KP_CONF    = 0.5f;
constexpr float NMS_THR    = 0.5f;

// Output layout (flat float32, reference return order):
//   scores  [NB*NQ]          offset 0
//   boxes   [NB*NQ*4]        offset NB*NQ
//   kps     [NB*NQ*NK*3]     offset NB*NQ*5
//   keep    [NB*NQ]          offset NB*NQ*5 + NB*NQ*NK*3
constexpr int OFF_BOXES = NB * NQ;
constexpr int OFF_KPS   = NB * NQ * 5;
constexpr int OFF_KEEP  = NB * NQ * 5 + NB * NQ * NK * 3;

constexpr int NBLK = 1024;            // 256 blocks per batch, 4 blocks/CU (all co-resident)

// ---------------- Fused kernel, v4: cost-balanced block-granularity ROI scan ----------------
// Round-4 post-mortem: phase 5 (one WAVE per (q,k), static round-robin) was
// ~28us of straggler tail -- item cost varies 100x (ROI area 1..16K px), so
// the phase ran at max-item latency, not total-work/waves. v4 keeps the
// verified v3 NMS (phases 0-4) and rebuilds phase 5: every block redundantly
// computes per-q chunk costs + prefix sums (deterministic, identical across
// blocks -> no communication), items are assigned to blocks by cost-midpoint
// partition, and each item is scanned by ALL 128 threads of its block with a
// wave-shuffle + cross-wave LDS argmax reduce. Worst block ~ share + max_item
// ~= 6K chunks / 128 lanes ~= 2-4us (vs ~25-30us tail before).
__global__ __launch_bounds__(128) void fused_kernel(
    const float* __restrict__ logits,   // [NB,NQ,2]
    const float* __restrict__ pboxes,   // [NB,NQ,4] cxcywh in [0,1]
    const float* __restrict__ hm,       // [NB,NK,NH,NW]
    const int* __restrict__ img_h_p,    // scalar
    const int* __restrict__ img_w_p,    // scalar
    float* __restrict__ out)            // 22800 floats
{
    const int blk = blockIdx.x;
    const int t   = threadIdx.x;
    const int b   = blk & 3;            // batch
    const int sub = blk >> 2;           // 0..255 within batch

    __shared__ float  skey[NQ];                 // valid ? score : -inf (original idx)
    __shared__ float4 srtb[104];                // rank -> xyxy box, zero-padded
    __shared__ unsigned long long smask0[NQ], smask1[NQ]; // IoU>thr bitmask per RANK row
    __shared__ unsigned long long svb[2];       // per-wave valid ballot
    __shared__ unsigned long long skmask[2];    // keep bits (rank space)
    __shared__ int sqpack[NQ];                  // per-ORIGINAL-q: 0 = dead, else packed ROI
    __shared__ int scq[NQ];                     // per-q chunk cost (0 if dead)
    __shared__ int sSq[NQ];                     // exclusive prefix of scq
    __shared__ unsigned short slist[NQ * NK];   // this block's item ids
    __shared__ int scount;
    __shared__ float sredv[2][2];               // cross-wave argmax combine (parity-buffered)
    __shared__ int   sredi[2][2];

    // ---- Early heatmap touch: one 64B line per thread covers all 4.45 MB
    // (poison just evicted caches). Barrier A drains it (~1us); phase 5 runs warm.
    float4 wv4 = make_float4(0.f, 0.f, 0.f, 0.f);
    const int  line = blk * 128 + t;
    const bool doW  = line < (NB * NK * NH * NW) / 16;
    if (doW) wv4 = ((const float4*)hm)[line * 4];

    const float iw = (float)img_w_p[0];
    const float ih = (float)img_h_p[0];
    const float sxl = (float)NW / iw;     // 0.25 exact for 512
    const float syl = (float)NH / ih;

    // ================= Phase 0: per-box score/valid/box (registers) =================
    if (t < 104) srtb[t] = make_float4(0.f, 0.f, 0.f, 0.f);   // pad rows -> IoU 0
    if (t == 0) scount = 0;

    float score = 0.f, x1 = 0.f, y1 = 0.f, x2 = 0.f, y2 = 0.f;
    bool valid = false;
    if (t < NQ) {
        const float2 lg = ((const float2*)logits)[b * NQ + t];   // 8B aligned
        const float m  = fmaxf(lg.x, lg.y);
        const float e0 = expf(lg.x - m);
        const float e1 = expf(lg.y - m);
        score = fmaxf(e0, e1) / (e0 + e1);
        const bool lab0 = (lg.x >= lg.y);

        const float4 pb = ((const float4*)pboxes)[b * NQ + t];   // 16B aligned
        x1 = (pb.x - 0.5f * pb.z) * iw;
        y1 = (pb.y - 0.5f * pb.w) * ih;
        x2 = (pb.x + 0.5f * pb.z) * iw;
        y2 = (pb.y + 0.5f * pb.w) * ih;

        valid = lab0 && (score >= HUMAN_CONF);
        skey[t] = valid ? score : -INFINITY;
    }
    {
        const unsigned long long vb = __ballot(valid);
        if ((t & 63) == 0) svb[t >> 6] = vb;
    }
    __syncthreads();   // A

    const int V = __popcll(svb[0]) + __popcll(svb[1]);   // # valid (uniform)

    // ================= Phase 1: rank (desc key, desc index) + scatter by rank ========
    int r = 0;
    if (t < NQ) {
        const float key = valid ? score : -INFINITY;
        for (int j = 0; j < NQ; j += 4) {
            const float a0 = skey[j + 0];
            const float a1 = skey[j + 1];
            const float a2 = skey[j + 2];
            const float a3 = skey[j + 3];
            r += (a0 > key || (a0 == key && (j + 0) > t)) ? 1 : 0;
            r += (a1 > key || (a1 == key && (j + 1) > t)) ? 1 : 0;
            r += (a2 > key || (a2 == key && (j + 2) > t)) ? 1 : 0;
            r += (a3 > key || (a3 == key && (j + 3) > t)) ? 1 : 0;
        }
        if (valid) srtb[r] = make_float4(x1, y1, x2, y2);
    }
    __syncthreads();   // B

    // ================= Phase 2: IoU bitmask rows (rank space, valid rows only) =======
    if (valid) {
        unsigned long long m0 = 0ull, m1 = 0ull;
        const float aa = fmaxf(x2 - x1, 0.f) * fmaxf(y2 - y1, 0.f);
        const int Vp = (V + 3) & ~3;                 // padded rows give IoU 0
        for (int j = 0; j < Vp; j += 4) {
            #pragma unroll
            for (int u = 0; u < 4; ++u) {
                const float4 bb = srtb[j + u];       // broadcast b128 read
                const float ba = fmaxf(bb.z - bb.x, 0.f) * fmaxf(bb.w - bb.y, 0.f);
                const float lx = fmaxf(x1, bb.x);
                const float ly = fmaxf(y1, bb.y);
                const float rx = fminf(x2, bb.z);
                const float ry = fminf(y2, bb.w);
                const float wv = fmaxf(rx - lx, 0.f);
                const float hv = fmaxf(ry - ly, 0.f);
                const float inter = wv * hv;
                const float uni = aa + ba - inter;
                const float iou = inter / fmaxf(uni, 1e-9f);   // identical expr to ref path
                if (iou > NMS_THR) {
                    const int jj = j + u;
                    if (jj < 64) m0 |= 1ull << jj; else m1 |= 1ull << (jj - 64);
                }
            }
        }
        smask0[r] = m0; smask1[r] = m1;
    }
    __syncthreads();   // C

    // ================= Phase 3: greedy keep via register rows + shfl (wave 0) ========
    if (t < 64) {
        const unsigned long long rm0 = smask0[t];
        const unsigned long long rm1 = smask1[t];

        unsigned long long rem0 = (V >= 64) ? ~0ull : ((1ull << V) - 1ull);
        unsigned long long rem1 = 0ull;
        if (V > 64) { const int v1 = V - 64; rem1 = (v1 >= 64) ? ~0ull : ((1ull << v1) - 1ull); }

        unsigned long long k0 = 0ull, k1 = 0ull;
        while (rem0 | rem1) {
            int i;
            unsigned long long bit0 = 0ull, bit1 = 0ull;
            if (rem0) { i = __builtin_ctzll(rem0); bit0 = 1ull << i; }
            else      { const int j = __builtin_ctzll(rem1); i = 64 + j; bit1 = 1ull << j; }
            k0 |= bit0; k1 |= bit1;
            unsigned long long row0, row1;
            if (i < 64) {                    // fast path: 2 shuffles
                row0 = __shfl(rm0, i);
                row1 = __shfl(rm1, i);
            } else {                         // rare fallback: LDS broadcast read
                row0 = smask0[i];
                row1 = smask1[i];
            }
            rem0 &= ~(row0 | bit0);          // self-clear handles degenerate boxes
            rem1 &= ~(row1 | bit1);
        }
        if (t == 0) { skmask[0] = k0; skmask[1] = k1; }
    }
    __syncthreads();   // D

    // ================= Phase 4: epilogue by ORIGINAL index + per-q cost =================
    if (t < NQ) {
        const unsigned long long k0s = skmask[0];
        const unsigned long long k1s = skmask[1];
        int kp = 0;
        if (valid) kp = (r < 64) ? (int)((k0s >> r) & 1ull)
                                 : (int)((k1s >> (r - 64)) & 1ull);

        const int bi0 = (int)x1;   // trunc toward zero == astype(int32)
        const int bi1 = (int)y1;
        const int bi2 = (int)x2;
        const int bi3 = (int)y2;

        // ROI bounds: int * 0.25f exact; trunc toward zero matches astype(int32).
        const int x1i = max((int)((float)bi0 * sxl), 0);
        const int y1i = max((int)((float)bi1 * syl), 0);
        const int x2i = min((int)((float)bi2 * sxl) + 1, NW);
        const int y2i = min((int)((float)bi3 * syl) + 1, NH);
        const bool live = kp && (x2i > x1i) && (y2i > y1i);

        // live => x2i >= 1 => pack != 0, so 0 is a safe dead sentinel.
        sqpack[t] = live ? (x1i | (y1i << 8) | (x2i << 16) | (y2i << 24)) : 0;

        // chunk cost of one (q,k) scan (same formulas as the scan itself)
        int cost = 0;
        if (live) {
            const int xa = x1i & ~3;
            const int C4 = (x2i - xa + 3) >> 2;
            cost = (y2i - y1i) * C4;
        }
        scq[t] = cost;

        if (sub == 0) {
            const int gi = b * NQ + t;
            out[gi] = score * (float)kp;
            out[OFF_BOXES + gi * 4 + 0] = (float)(bi0 * kp);
            out[OFF_BOXES + gi * 4 + 1] = (float)(bi1 * kp);
            out[OFF_BOXES + gi * 4 + 2] = (float)(bi2 * kp);
            out[OFF_BOXES + gi * 4 + 3] = (float)(bi3 * kp);
            out[OFF_KEEP + gi] = (float)kp;
        }
    }
    __syncthreads();   // E

    // Consume the warm touch (waitcnt already drained at barrier A; keeps load live).
    if (doW) asm volatile("" :: "v"(wv4.x), "v"(wv4.y), "v"(wv4.z), "v"(wv4.w));

    // ================= Phase 5a: prefix sums over per-q costs =================
    // Uniform broadcast reads; every thread also accumulates the grand total.
    int pref = 0, tcq = 0;
    for (int j = 0; j < NQ; j += 4) {
        #pragma unroll
        for (int u = 0; u < 4; ++u) {
            const int c = scq[j + u];
            tcq += c;
            pref += ((j + u) < t) ? c : 0;
        }
    }
    if (t < NQ) sSq[t] = pref;
    __syncthreads();   // F

    // ================= Phase 5b: membership sweep + dead-item zero writes =================
    // Item (q,k) id g = q*17+k; cost c_q; exclusive prefix S_g = 17*Sq[q] + k*c_q.
    // Cost-midpoint partition: bin(g) = (2*S_g + c_q) / (2*ceil(TC/256)).
    // Deterministic and identical in every block -> each live item claimed by
    // exactly one block. Dead items: zero-written by owner block (g mod 256).
    const int TC = 17 * tcq;
    const int binsz2 = 2 * ((TC + 255) >> 8);

    for (int g = t; g < NQ * NK; g += 128) {
        const int q = g / NK;                 // const divisor -> magic mul
        const int k = g - q * NK;
        const int pack = sqpack[q];
        if (pack == 0) {
            if ((g & 255) == sub) {
                float* kout = out + OFF_KPS + (size_t)(b * NQ + q) * (NK * 3) + k * 3;
                kout[0] = 0.0f; kout[1] = 0.0f; kout[2] = 0.0f;
            }
        } else {
            const int c  = scq[q];
            const int m2 = 34 * sSq[q] + (2 * k + 1) * c;    // 2*midpoint, < 2*TC (fits i32)
            if (m2 / binsz2 == sub) {
                const int pos = atomicAdd(&scount, 1);
                slist[pos] = (unsigned short)g;
            }
        }
    }
    __syncthreads();   // G

    // ================= Phase 5c: scan items, ALL 128 threads per item =================
    const int icount = scount;                // uniform
    for (int n = 0; n < icount; ++n) {
        const int id = slist[n];              // uniform LDS broadcast
        const int q  = id / NK;
        const int k  = id - q * NK;
        const int pack = sqpack[q];           // live by construction
        const int x1r = pack & 255;
        const int y1r = (pack >> 8) & 255;
        const int x2r = (pack >> 16) & 255;
        const int y2r = (pack >> 24) & 255;
        const int gi  = b * NQ + q;

        const float4* __restrict__ b4 =
            (const float4*)(hm + (size_t)(b * NK + k) * (NH * NW));   // 64KB-aligned

        const int xa     = x1r & ~3;                    // align ROI left edge down
        const int C4     = (x2r - xa + 3) >> 2;         // float4 chunks per row, 1..32
        const int R      = y2r - y1r;
        const int total4 = R * C4;                      // < 2^12
        const unsigned M = (C4 > 1) ? (0xFFFFFFFFu / (unsigned)C4 + 1u) : 0u;

        float best = -INFINITY;
        int   bidx = 0x7fffffff;                        // global flat idx y*NW+x

        auto proc = [&](int idx, float4 v) {
            const int row = (C4 == 1) ? idx : (int)__umulhi((unsigned)idx, M);
            const int xb  = xa + (idx - row * C4) * 4;
            const int g   = (y1r + row) * NW + xb;
            // component order = increasing x = increasing flat idx; strict > keeps
            // the earliest occurrence (argmax tie semantics)
            const float v0 = (xb + 0 >= x1r && xb + 0 < x2r) ? v.x : -INFINITY;
            const float v1 = (xb + 1 >= x1r && xb + 1 < x2r) ? v.y : -INFINITY;
            const float v2 = (xb + 2 >= x1r && xb + 2 < x2r) ? v.z : -INFINITY;
            const float v3 = (xb + 3 < x2r) ? v.w : -INFINITY;
            if (v0 > best) { best = v0; bidx = g + 0; }
            if (v1 > best) { best = v1; bidx = g + 1; }
            if (v2 > best) { best = v2; bidx = g + 2; }
            if (v3 > best) { best = v3; bidx = g + 3; }
        };
        auto caddr = [&](int idx) {
            const int row = (C4 == 1) ? idx : (int)__umulhi((unsigned)idx, M);
            return (y1r + row) * (NW / 4) + (xa >> 2) + (idx - row * C4);
        };

        int idx = t;   // 0..127, stride 128; 4 chunk-loads in flight per iteration
        for (; idx + 384 < total4; idx += 512) {
            const int a0 = caddr(idx), a1 = caddr(idx + 128), a2 = caddr(idx + 256), a3 = caddr(idx + 384);
            const float4 v0 = b4[a0];
            const float4 v1 = b4[a1];
            const float4 v2 = b4[a2];
            const float4 v3 = b4[a3];
            proc(idx, v0);
            proc(idx + 128, v1);
            proc(idx + 256, v2);
            proc(idx + 384, v3);
        }
        for (; idx < total4; idx += 128) proc(idx, b4[caddr(idx)]);

        // 64-lane shuffle argmax reduce per wave; tie -> smaller flat index
        for (int off = 32; off >= 1; off >>= 1) {
            const float ov = __shfl_down(best, off);
            const int   oi = __shfl_down(bidx, off);
            if (ov > best || (ov == best && oi < bidx)) { best = ov; bidx = oi; }
        }
        if ((t & 63) == 0) { sredv[n & 1][t >> 6] = best; sredi[n & 1][t >> 6] = bidx; }
        __syncthreads();   // parity buffer -> one barrier per item is sufficient

        if (t == 0) {
            float bv = sredv[n & 1][0]; int bi = sredi[n & 1][0];
            const float ov = sredv[n & 1][1]; const int oi = sredi[n & 1][1];
            if (ov > bv || (ov == bv && oi < bi)) { bv = ov; bi = oi; }
            const int col = bi & (NW - 1);
            const int row = bi >> 7;
            float conf = bv;
            if (conf < KP_CONF) conf = 0.0f;
            float* kout = out + OFF_KPS + (size_t)gi * (NK * 3) + k * 3;
            kout[0] = (float)col / sxl;
            kout[1] = (float)row / syl;
            kout[2] = conf;
        }
    }
}

extern "C" void kernel_launch(void* const* d_in, const int* in_sizes, int n_in,
                              void* d_out, int out_size, void* d_ws, size_t ws_size,
                              hipStream_t stream) {
    const float* logits = (const float*)d_in[0];   // [4,100,2]
    const float* pboxes = (const float*)d_in[1];   // [4,100,4]
    const float* hm     = (const float*)d_in[2];   // [4,17,128,128]
    const int*   img_h  = (const int*)d_in[3];
    const int*   img_w  = (const int*)d_in[4];
    float* out = (float*)d_out;

    fused_kernel<<<NBLK, 128, 0, stream>>>(logits, pboxes, hm, img_h, img_w, out);
}

// Round 6
// 98.100 us; speedup vs baseline: 1.2192x; 1.2192x over previous
//
#include <hip/hip_runtime.h>
#include <cmath>
#include <cfloat>

// Problem constants (fixed by setup_inputs: B=4, Q=100, K=17, H=W=128).
constexpr int NB = 4;
constexpr int NQ = 100;
constexpr int NK = 17;
constexpr int NH = 128;
constexpr int NW = 128;

constexpr float HUMAN_CONF = 0.7f;
constexpr float KP_CONF    = 0.5f;
constexpr float NMS_THR    = 0.5f;

// Output layout (flat float32, reference return order):
//   scores  [NB*NQ]          offset 0
//   boxes   [NB*NQ*4]        offset NB*NQ
//   kps     [NB*NQ*NK*3]     offset NB*NQ*5
//   keep    [NB*NQ]          offset NB*NQ*5 + NB*NQ*NK*3
constexpr int OFF_BOXES = NB * NQ;
constexpr int OFF_KPS   = NB * NQ * 5;
constexpr int OFF_KEEP  = NB * NQ * 5 + NB * NQ * NK * 3;

constexpr int NBLK = 1024;   // 256 blocks per batch, 4 blocks/CU (all co-resident)
constexpr int OV   = 96;     // per-item fixed overhead in chunk-equivalents (cost model)

// ---------------- Fused kernel, v5: wave-granularity cost-balanced ROI scan ----------------
// Round-5 post-mortem: v4 balanced chunk COST but not ITEM COUNT, and paid a
// block-wide barrier + LDS combine per item (~0.5us fixed). Cheap items
// cluster into one bin -> one block serially ate dozens of them (58us).
// v5 fixes the mechanism: (1) items processed at WAVE granularity (64 lanes,
// shuffle reduce only -- no barriers, no cross-wave combine; 512 wave-bins
// per batch); (2) cost model is chunks + OV so cheap-item clusters spread
// across bins (17 items span >= 17*(1+OV) > binsize) and items/wave is
// bounded by binsize/(1+OV)+1. Worst wave ~ bin share (~800) + max item
// (~4300) ~= 5K chunk-equiv ~= 2us. NMS phases 0-4 byte-identical to the
// verified v3/v4 path.
__global__ __launch_bounds__(128) void fused_kernel(
    const float* __restrict__ logits,   // [NB,NQ,2]
    const float* __restrict__ pboxes,   // [NB,NQ,4] cxcywh in [0,1]
    const float* __restrict__ hm,       // [NB,NK,NH,NW]
    const int* __restrict__ img_h_p,    // scalar
    const int* __restrict__ img_w_p,    // scalar
    float* __restrict__ out)            // 22800 floats
{
    const int blk = blockIdx.x;
    const int t   = threadIdx.x;
    const int b   = blk & 3;            // batch
    const int sub = blk >> 2;           // 0..255 within batch

    __shared__ float  skey[NQ];                 // valid ? score : -inf (original idx)
    __shared__ float4 srtb[104];                // rank -> xyxy box, zero-padded
    __shared__ unsigned long long smask0[NQ], smask1[NQ]; // IoU>thr bitmask per RANK row
    __shared__ unsigned long long svb[2];       // per-wave valid ballot
    __shared__ unsigned long long skmask[2];    // keep bits (rank space)
    __shared__ int sqpack[NQ];                  // per-ORIGINAL-q: 0 = dead, else packed ROI
    __shared__ int scq[NQ];                     // per-q item cost' = chunks+OV (0 if dead)
    __shared__ int sSq[NQ];                     // exclusive prefix of scq

    // ---- Early heatmap touch: one 64B line per thread covers all 4.45 MB
    // (poison just evicted caches). Drained at barrier A; phase 5 runs warm.
    float4 wv4 = make_float4(0.f, 0.f, 0.f, 0.f);
    const int  line = blk * 128 + t;
    const bool doW  = line < (NB * NK * NH * NW) / 16;
    if (doW) wv4 = ((const float4*)hm)[line * 4];

    const float iw = (float)img_w_p[0];
    const float ih = (float)img_h_p[0];
    const float sxl = (float)NW / iw;     // 0.25 exact for 512
    const float syl = (float)NH / ih;

    // ================= Phase 0: per-box score/valid/box (registers) =================
    if (t < 104) srtb[t] = make_float4(0.f, 0.f, 0.f, 0.f);   // pad rows -> IoU 0

    float score = 0.f, x1 = 0.f, y1 = 0.f, x2 = 0.f, y2 = 0.f;
    bool valid = false;
    if (t < NQ) {
        const float2 lg = ((const float2*)logits)[b * NQ + t];   // 8B aligned
        const float m  = fmaxf(lg.x, lg.y);
        const float e0 = expf(lg.x - m);
        const float e1 = expf(lg.y - m);
        score = fmaxf(e0, e1) / (e0 + e1);
        const bool lab0 = (lg.x >= lg.y);

        const float4 pb = ((const float4*)pboxes)[b * NQ + t];   // 16B aligned
        x1 = (pb.x - 0.5f * pb.z) * iw;
        y1 = (pb.y - 0.5f * pb.w) * ih;
        x2 = (pb.x + 0.5f * pb.z) * iw;
        y2 = (pb.y + 0.5f * pb.w) * ih;

        valid = lab0 && (score >= HUMAN_CONF);
        skey[t] = valid ? score : -INFINITY;
    }
    {
        const unsigned long long vb = __ballot(valid);
        if ((t & 63) == 0) svb[t >> 6] = vb;
    }
    __syncthreads();   // A

    const int V = __popcll(svb[0]) + __popcll(svb[1]);   // # valid (uniform)

    // ================= Phase 1: rank (desc key, desc index) + scatter by rank ========
    int r = 0;
    if (t < NQ) {
        const float key = valid ? score : -INFINITY;
        for (int j = 0; j < NQ; j += 4) {
            const float a0 = skey[j + 0];
            const float a1 = skey[j + 1];
            const float a2 = skey[j + 2];
            const float a3 = skey[j + 3];
            r += (a0 > key || (a0 == key && (j + 0) > t)) ? 1 : 0;
            r += (a1 > key || (a1 == key && (j + 1) > t)) ? 1 : 0;
            r += (a2 > key || (a2 == key && (j + 2) > t)) ? 1 : 0;
            r += (a3 > key || (a3 == key && (j + 3) > t)) ? 1 : 0;
        }
        if (valid) srtb[r] = make_float4(x1, y1, x2, y2);
    }
    __syncthreads();   // B

    // ================= Phase 2: IoU bitmask rows (rank space, valid rows only) =======
    if (valid) {
        unsigned long long m0 = 0ull, m1 = 0ull;
        const float aa = fmaxf(x2 - x1, 0.f) * fmaxf(y2 - y1, 0.f);
        const int Vp = (V + 3) & ~3;                 // padded rows give IoU 0
        for (int j = 0; j < Vp; j += 4) {
            #pragma unroll
            for (int u = 0; u < 4; ++u) {
                const float4 bb = srtb[j + u];       // broadcast b128 read
                const float ba = fmaxf(bb.z - bb.x, 0.f) * fmaxf(bb.w - bb.y, 0.f);
                const float lx = fmaxf(x1, bb.x);
                const float ly = fmaxf(y1, bb.y);
                const float rx = fminf(x2, bb.z);
                const float ry = fminf(y2, bb.w);
                const float wv = fmaxf(rx - lx, 0.f);
                const float hv = fmaxf(ry - ly, 0.f);
                const float inter = wv * hv;
                const float uni = aa + ba - inter;
                const float iou = inter / fmaxf(uni, 1e-9f);   // identical expr to ref path
                if (iou > NMS_THR) {
                    const int jj = j + u;
                    if (jj < 64) m0 |= 1ull << jj; else m1 |= 1ull << (jj - 64);
                }
            }
        }
        smask0[r] = m0; smask1[r] = m1;
    }
    __syncthreads();   // C

    // ================= Phase 3: greedy keep via register rows + shfl (wave 0) ========
    if (t < 64) {
        const unsigned long long rm0 = smask0[t];
        const unsigned long long rm1 = smask1[t];

        unsigned long long rem0 = (V >= 64) ? ~0ull : ((1ull << V) - 1ull);
        unsigned long long rem1 = 0ull;
        if (V > 64) { const int v1 = V - 64; rem1 = (v1 >= 64) ? ~0ull : ((1ull << v1) - 1ull); }

        unsigned long long k0 = 0ull, k1 = 0ull;
        while (rem0 | rem1) {
            int i;
            unsigned long long bit0 = 0ull, bit1 = 0ull;
            if (rem0) { i = __builtin_ctzll(rem0); bit0 = 1ull << i; }
            else      { const int j = __builtin_ctzll(rem1); i = 64 + j; bit1 = 1ull << j; }
            k0 |= bit0; k1 |= bit1;
            unsigned long long row0, row1;
            if (i < 64) {                    // fast path: 2 shuffles
                row0 = __shfl(rm0, i);
                row1 = __shfl(rm1, i);
            } else {                         // rare fallback: LDS broadcast read
                row0 = smask0[i];
                row1 = smask1[i];
            }
            rem0 &= ~(row0 | bit0);          // self-clear handles degenerate boxes
            rem1 &= ~(row1 | bit1);
        }
        if (t == 0) { skmask[0] = k0; skmask[1] = k1; }
    }
    __syncthreads();   // D

    // ================= Phase 4: epilogue by ORIGINAL index + per-q item cost' =========
    if (t < NQ) {
        const unsigned long long k0s = skmask[0];
        const unsigned long long k1s = skmask[1];
        int kp = 0;
        if (valid) kp = (r < 64) ? (int)((k0s >> r) & 1ull)
                                 : (int)((k1s >> (r - 64)) & 1ull);

        const int bi0 = (int)x1;   // trunc toward zero == astype(int32)
        const int bi1 = (int)y1;
        const int bi2 = (int)x2;
        const int bi3 = (int)y2;

        // ROI bounds: int * 0.25f exact; trunc toward zero matches astype(int32).
        const int x1i = max((int)((float)bi0 * sxl), 0);
        const int y1i = max((int)((float)bi1 * syl), 0);
        const int x2i = min((int)((float)bi2 * sxl) + 1, NW);
        const int y2i = min((int)((float)bi3 * syl) + 1, NH);
        const bool live = kp && (x2i > x1i) && (y2i > y1i);

        // live => x2i >= 1 => pack != 0, so 0 is a safe dead sentinel.
        sqpack[t] = live ? (x1i | (y1i << 8) | (x2i << 16) | (y2i << 24)) : 0;

        // item cost' = scan chunks + OV (per-item fixed overhead); 0 marks dead.
        int cost = 0;
        if (live) {
            const int xa = x1i & ~3;
            const int C4 = (x2i - xa + 3) >> 2;
            cost = (y2i - y1i) * C4 + OV;
        }
        scq[t] = cost;

        if (sub == 0) {
            const int gi = b * NQ + t;
            out[gi] = score * (float)kp;
            out[OFF_BOXES + gi * 4 + 0] = (float)(bi0 * kp);
            out[OFF_BOXES + gi * 4 + 1] = (float)(bi1 * kp);
            out[OFF_BOXES + gi * 4 + 2] = (float)(bi2 * kp);
            out[OFF_BOXES + gi * 4 + 3] = (float)(bi3 * kp);
            out[OFF_KEEP + gi] = (float)kp;
        }
    }
    __syncthreads();   // E

    // Consume the warm touch (drained at barrier A; keeps the load live).
    if (doW) asm volatile("" :: "v"(wv4.x), "v"(wv4.y), "v"(wv4.z), "v"(wv4.w));

    // ================= Phase 5a: prefix sums over per-q item costs =================
    int pref = 0, tcq = 0;
    for (int j = 0; j < NQ; j += 4) {
        #pragma unroll
        for (int u = 0; u < 4; ++u) {
            const int c = scq[j + u];
            tcq += c;
            pref += ((j + u) < t) ? c : 0;
        }
    }
    if (t < NQ) sSq[t] = pref;
    __syncthreads();   // F

    // ================= Phase 5b: dead-item zero writes (one owner block each) ========
    for (int g = t; g < NQ * NK; g += 128) {
        const int q = g / NK;                 // const divisor -> magic mul
        if (sqpack[q] == 0 && (g & 255) == sub) {
            const int k = g - q * NK;
            float* kout = out + OFF_KPS + (size_t)(b * NQ + q) * (NK * 3) + k * 3;
            kout[0] = 0.0f; kout[1] = 0.0f; kout[2] = 0.0f;
        }
    }

    // ================= Phase 5c: wave-bin membership sweep + inline item scan ========
    // Item (q,k): cost' c=scq[q], exclusive prefix S = 17*sSq[q] + k*c (item
    // order), midpoint*2 m2 = 2S + c. wave-bin = m2 / binsz2, 512 bins/batch.
    // Deterministic + identical across blocks -> exactly one owner wave per
    // item, no communication. Ballot sweep: 64 membership tests at a time,
    // then the whole wave processes each set bit's item (shuffle reduce only,
    // no barriers).
    const int lane = t & 63;
    const int wbin = sub * 2 + (t >> 6);          // this wave's bin, 0..511
    const int TC2  = 17 * tcq;                    // 2*? no: total cost' (x17 items/q)
    const int binsz2 = max(2 * ((TC2 + 511) >> 9), 2);

    for (int g0 = 0; g0 < NQ * NK; g0 += 64) {
        const int g = g0 + lane;
        bool mine = false;
        if (g < NQ * NK) {
            const int q = g / NK;
            const int k = g - q * NK;
            const int c = scq[q];                 // LDS broadcast-ish read
            if (c != 0) {
                const int m2 = 34 * sSq[q] + (2 * k + 1) * c;   // < 2*TC2 < 2^25
                mine = (m2 / binsz2) == wbin;
            }
        }
        unsigned long long mask = __ballot(mine);
        while (mask) {
            const int bit = __builtin_ctzll(mask);
            mask &= mask - 1;
            const int id = g0 + bit;              // uniform item id for the wave

            const int q  = id / NK;
            const int k  = id - q * NK;
            const int pack = sqpack[q];           // live by construction
            const int x1r = pack & 255;
            const int y1r = (pack >> 8) & 255;
            const int x2r = (pack >> 16) & 255;
            const int y2r = (pack >> 24) & 255;
            const int gi  = b * NQ + q;

            const float4* __restrict__ b4 =
                (const float4*)(hm + (size_t)(b * NK + k) * (NH * NW));   // 64KB-aligned

            const int xa     = x1r & ~3;                    // align ROI left edge down
            const int C4     = (x2r - xa + 3) >> 2;         // float4 chunks per row, 1..32
            const int R      = y2r - y1r;
            const int total4 = R * C4;                      // < 2^12
            const unsigned M = (C4 > 1) ? (0xFFFFFFFFu / (unsigned)C4 + 1u) : 0u;

            float best = -INFINITY;
            int   bidx = 0x7fffffff;                        // global flat idx y*NW+x

            auto proc = [&](int idx, float4 v) {
                const int row = (C4 == 1) ? idx : (int)__umulhi((unsigned)idx, M);
                const int xb  = xa + (idx - row * C4) * 4;
                const int g2  = (y1r + row) * NW + xb;
                // component order = increasing x = increasing flat idx; strict >
                // keeps the earliest occurrence (argmax tie semantics)
                const float v0 = (xb + 0 >= x1r && xb + 0 < x2r) ? v.x : -INFINITY;
                const float v1 = (xb + 1 >= x1r && xb + 1 < x2r) ? v.y : -INFINITY;
                const float v2 = (xb + 2 >= x1r && xb + 2 < x2r) ? v.z : -INFINITY;
                const float v3 = (xb + 3 < x2r) ? v.w : -INFINITY;
                if (v0 > best) { best = v0; bidx = g2 + 0; }
                if (v1 > best) { best = v1; bidx = g2 + 1; }
                if (v2 > best) { best = v2; bidx = g2 + 2; }
                if (v3 > best) { best = v3; bidx = g2 + 3; }
            };
            auto caddr = [&](int idx) {
                const int row = (C4 == 1) ? idx : (int)__umulhi((unsigned)idx, M);
                return (y1r + row) * (NW / 4) + (xa >> 2) + (idx - row * C4);
            };

            int idx = lane;
            // 4 chunk-loads in flight per iteration (16 values).
            for (; idx + 192 < total4; idx += 256) {
                const int a0 = caddr(idx), a1 = caddr(idx + 64), a2 = caddr(idx + 128), a3 = caddr(idx + 192);
                const float4 v0 = b4[a0];
                const float4 v1 = b4[a1];
                const float4 v2 = b4[a2];
                const float4 v3 = b4[a3];
                proc(idx, v0);
                proc(idx + 64, v1);
                proc(idx + 128, v2);
                proc(idx + 192, v3);
            }
            for (; idx < total4; idx += 64) proc(idx, b4[caddr(idx)]);

            // 64-lane shuffle argmax reduce; tie -> smaller flat index
            for (int off = 32; off >= 1; off >>= 1) {
                const float ov = __shfl_down(best, off);
                const int   oi = __shfl_down(bidx, off);
                if (ov > best || (ov == best && oi < bidx)) { best = ov; bidx = oi; }
            }

            if (lane == 0) {
                const int col = bidx & (NW - 1);
                const int row = bidx >> 7;
                float conf = best;
                if (conf < KP_CONF) conf = 0.0f;
                float* kout = out + OFF_KPS + (size_t)gi * (NK * 3) + k * 3;
                kout[0] = (float)col / sxl;
                kout[1] = (float)row / syl;
                kout[2] = conf;
            }
        }
    }
}

extern "C" void kernel_launch(void* const* d_in, const int* in_sizes, int n_in,
                              void* d_out, int out_size, void* d_ws, size_t ws_size,
                              hipStream_t stream) {
    const float* logits = (const float*)d_in[0];   // [4,100,2]
    const float* pboxes = (const float*)d_in[1];   // [4,100,4]
    const float* hm     = (const float*)d_in[2];   // [4,17,128,128]
    const int*   img_h  = (const int*)d_in[3];
    const int*   img_w  = (const int*)d_in[4];
    float* out = (float*)d_out;

    fused_kernel<<<NBLK, 128, 0, stream>>>(logits, pboxes, hm, img_h, img_w, out);
}

// Round 7
// 97.017 us; speedup vs baseline: 1.2329x; 1.0112x over previous
//
#include <hip/hip_runtime.h>
#include <cmath>
#include <cfloat>

// Problem constants (fixed by setup_inputs: B=4, Q=100, K=17, H=W=128).
constexpr int NB = 4;
constexpr int NQ = 100;
constexpr int NK = 17;
constexpr int NH = 128;
constexpr int NW = 128;

constexpr float HUMAN_CONF = 0.7f;
constexpr float KP_CONF    = 0.5f;
constexpr float NMS_THR    = 0.5f;

// Output layout (flat float32, reference return order):
//   scores  [NB*NQ]          offset 0
//   boxes   [NB*NQ*4]        offset NB*NQ
//   kps     [NB*NQ*NK*3]     offset NB*NQ*5
//   keep    [NB*NQ]          offset NB*NQ*5 + NB*NQ*NK*3
constexpr int OFF_BOXES = NB * NQ;
constexpr int OFF_KPS   = NB * NQ * 5;
constexpr int OFF_KEEP  = NB * NQ * 5 + NB * NQ * NK * 3;

constexpr int K2_BLOCKS = 2048;                    // 512 blocks/batch, 8 blocks/CU
constexpr int K2_WPB    = (K2_BLOCKS / NB) * 2;    // 1024 waves per batch

// ---------------- K1: NMS once, 4 blocks (one per batch) ----------------
// v3/v5-verified phases 0-4. Publishes per-q packed ROI (0 = dead) to ws;
// kernel-dispatch boundary makes it visible to K2 (round-1-verified path).
__global__ __launch_bounds__(128) void nms_kernel(
    const float* __restrict__ logits,   // [NB,NQ,2]
    const float* __restrict__ pboxes,   // [NB,NQ,4] cxcywh in [0,1]
    const int* __restrict__ img_h_p,    // scalar
    const int* __restrict__ img_w_p,    // scalar
    float* __restrict__ out,            // 22800 floats
    int* __restrict__ qpack)            // ws: [NB*NQ] packed ROI or 0
{
    const int b = blockIdx.x;
    const int t = threadIdx.x;

    __shared__ float  skey[NQ];                 // valid ? score : -inf (original idx)
    __shared__ float4 srtb[104];                // rank -> xyxy box, zero-padded
    __shared__ unsigned long long smask0[NQ], smask1[NQ]; // IoU>thr bitmask per RANK row
    __shared__ unsigned long long svb[2];       // per-wave valid ballot
    __shared__ unsigned long long skmask[2];    // keep bits (rank space)

    const float iw = (float)img_w_p[0];
    const float ih = (float)img_h_p[0];
    const float sxl = (float)NW / iw;     // 0.25 exact for 512
    const float syl = (float)NH / ih;

    // ================= Phase 0: per-box score/valid/box (registers) =================
    if (t < 104) srtb[t] = make_float4(0.f, 0.f, 0.f, 0.f);   // pad rows -> IoU 0

    float score = 0.f, x1 = 0.f, y1 = 0.f, x2 = 0.f, y2 = 0.f;
    bool valid = false;
    if (t < NQ) {
        const float2 lg = ((const float2*)logits)[b * NQ + t];   // 8B aligned
        const float m  = fmaxf(lg.x, lg.y);
        const float e0 = expf(lg.x - m);
        const float e1 = expf(lg.y - m);
        score = fmaxf(e0, e1) / (e0 + e1);
        const bool lab0 = (lg.x >= lg.y);

        const float4 pb = ((const float4*)pboxes)[b * NQ + t];   // 16B aligned
        x1 = (pb.x - 0.5f * pb.z) * iw;
        y1 = (pb.y - 0.5f * pb.w) * ih;
        x2 = (pb.x + 0.5f * pb.z) * iw;
        y2 = (pb.y + 0.5f * pb.w) * ih;

        valid = lab0 && (score >= HUMAN_CONF);
        skey[t] = valid ? score : -INFINITY;
    }
    {
        const unsigned long long vb = __ballot(valid);
        if ((t & 63) == 0) svb[t >> 6] = vb;
    }
    __syncthreads();   // A

    const int V = __popcll(svb[0]) + __popcll(svb[1]);   // # valid (uniform)

    // ================= Phase 1: rank (desc key, desc index) + scatter by rank ========
    int r = 0;
    if (t < NQ) {
        const float key = valid ? score : -INFINITY;
        for (int j = 0; j < NQ; j += 4) {
            const float a0 = skey[j + 0];
            const float a1 = skey[j + 1];
            const float a2 = skey[j + 2];
            const float a3 = skey[j + 3];
            r += (a0 > key || (a0 == key && (j + 0) > t)) ? 1 : 0;
            r += (a1 > key || (a1 == key && (j + 1) > t)) ? 1 : 0;
            r += (a2 > key || (a2 == key && (j + 2) > t)) ? 1 : 0;
            r += (a3 > key || (a3 == key && (j + 3) > t)) ? 1 : 0;
        }
        if (valid) srtb[r] = make_float4(x1, y1, x2, y2);
    }
    __syncthreads();   // B

    // ================= Phase 2: IoU bitmask rows (rank space, valid rows only) =======
    if (valid) {
        unsigned long long m0 = 0ull, m1 = 0ull;
        const float aa = fmaxf(x2 - x1, 0.f) * fmaxf(y2 - y1, 0.f);
        const int Vp = (V + 3) & ~3;                 // padded rows give IoU 0
        for (int j = 0; j < Vp; j += 4) {
            #pragma unroll
            for (int u = 0; u < 4; ++u) {
                const float4 bb = srtb[j + u];       // broadcast b128 read
                const float ba = fmaxf(bb.z - bb.x, 0.f) * fmaxf(bb.w - bb.y, 0.f);
                const float lx = fmaxf(x1, bb.x);
                const float ly = fmaxf(y1, bb.y);
                const float rx = fminf(x2, bb.z);
                const float ry = fminf(y2, bb.w);
                const float wv = fmaxf(rx - lx, 0.f);
                const float hv = fmaxf(ry - ly, 0.f);
                const float inter = wv * hv;
                const float uni = aa + ba - inter;
                const float iou = inter / fmaxf(uni, 1e-9f);   // identical expr to ref path
                if (iou > NMS_THR) {
                    const int jj = j + u;
                    if (jj < 64) m0 |= 1ull << jj; else m1 |= 1ull << (jj - 64);
                }
            }
        }
        smask0[r] = m0; smask1[r] = m1;
    }
    __syncthreads();   // C

    // ================= Phase 3: greedy keep via register rows + shfl (wave 0) ========
    if (t < 64) {
        const unsigned long long rm0 = smask0[t];
        const unsigned long long rm1 = smask1[t];

        unsigned long long rem0 = (V >= 64) ? ~0ull : ((1ull << V) - 1ull);
        unsigned long long rem1 = 0ull;
        if (V > 64) { const int v1 = V - 64; rem1 = (v1 >= 64) ? ~0ull : ((1ull << v1) - 1ull); }

        unsigned long long k0 = 0ull, k1 = 0ull;
        while (rem0 | rem1) {
            int i;
            unsigned long long bit0 = 0ull, bit1 = 0ull;
            if (rem0) { i = __builtin_ctzll(rem0); bit0 = 1ull << i; }
            else      { const int j = __builtin_ctzll(rem1); i = 64 + j; bit1 = 1ull << j; }
            k0 |= bit0; k1 |= bit1;
            unsigned long long row0, row1;
            if (i < 64) {                    // fast path: 2 shuffles
                row0 = __shfl(rm0, i);
                row1 = __shfl(rm1, i);
            } else {                         // rare fallback: LDS broadcast read
                row0 = smask0[i];
                row1 = smask1[i];
            }
            rem0 &= ~(row0 | bit0);          // self-clear handles degenerate boxes
            rem1 &= ~(row1 | bit1);
        }
        if (t == 0) { skmask[0] = k0; skmask[1] = k1; }
    }
    __syncthreads();   // D

    // ================= Phase 4: epilogue by ORIGINAL index -> out + qpack ============
    if (t < NQ) {
        const unsigned long long k0s = skmask[0];
        const unsigned long long k1s = skmask[1];
        int kp = 0;
        if (valid) kp = (r < 64) ? (int)((k0s >> r) & 1ull)
                                 : (int)((k1s >> (r - 64)) & 1ull);

        const int bi0 = (int)x1;   // trunc toward zero == astype(int32)
        const int bi1 = (int)y1;
        const int bi2 = (int)x2;
        const int bi3 = (int)y2;

        // ROI bounds: int * 0.25f exact; trunc toward zero matches astype(int32).
        const int x1i = max((int)((float)bi0 * sxl), 0);
        const int y1i = max((int)((float)bi1 * syl), 0);
        const int x2i = min((int)((float)bi2 * sxl) + 1, NW);
        const int y2i = min((int)((float)bi3 * syl) + 1, NH);
        const bool live = kp && (x2i > x1i) && (y2i > y1i);

        const int gi = b * NQ + t;
        // live => x2i >= 1 => pack != 0, so 0 is a safe dead sentinel.
        qpack[gi] = live ? (x1i | (y1i << 8) | (x2i << 16) | (y2i << 24)) : 0;

        out[gi] = score * (float)kp;
        out[OFF_BOXES + gi * 4 + 0] = (float)(bi0 * kp);
        out[OFF_BOXES + gi * 4 + 1] = (float)(bi1 * kp);
        out[OFF_BOXES + gi * 4 + 2] = (float)(bi2 * kp);
        out[OFF_BOXES + gi * 4 + 3] = (float)(bi3 * kp);
        out[OFF_KEEP + gi] = (float)kp;
    }
}

// ---------------- K2: ROI keypoint scan, no NMS redundancy ----------------
// 2048 blocks (8/CU -> 4 waves/SIMD of latency hiding, 4x the fused version).
// Per block: load this batch's 100-entry qpack table into LDS, then v3's
// proven static round-robin: one wave per (q,k) item, <=2 items/wave, dead
// items write their 3 zeros exactly once.
__global__ __launch_bounds__(128) void scan_kernel(
    const float* __restrict__ hm,       // [NB,NK,NH,NW]
    const int* __restrict__ qpack,      // ws: [NB*NQ]
    const int* __restrict__ img_h_p,
    const int* __restrict__ img_w_p,
    float* __restrict__ out)
{
    const int blk = blockIdx.x;
    const int t   = threadIdx.x;
    const int b   = blk & 3;            // batch
    const int sub = blk >> 2;           // 0..511 within batch

    __shared__ int sqpack[NQ];

    // Warm touch: first 544 blocks cover all 4.45 MB of heatmap, one 64B line
    // per thread; drained at the barrier below -> scan runs LLC-warm.
    float4 wv4 = make_float4(0.f, 0.f, 0.f, 0.f);
    const int  line = blk * 128 + t;
    const bool doW  = line < (NB * NK * NH * NW) / 16;
    if (doW) wv4 = ((const float4*)hm)[line * 4];

    if (t < NQ) sqpack[t] = qpack[b * NQ + t];
    __syncthreads();
    if (doW) asm volatile("" :: "v"(wv4.x), "v"(wv4.y), "v"(wv4.z), "v"(wv4.w));

    const float sxl = (float)NW / (float)img_w_p[0];
    const float syl = (float)NH / (float)img_h_p[0];

    const int lane = t & 63;
    const int wvid = sub * 2 + (t >> 6);          // wave id within batch, 0..1023

    for (int item = wvid; item < NQ * NK; item += K2_WPB) {
        const int q = item / NK;                  // const divisor -> magic mul
        const int k = item - q * NK;
        const int gi = b * NQ + q;
        float* kout = out + OFF_KPS + (size_t)gi * (NK * 3) + k * 3;

        const int pack = sqpack[q];               // wave-uniform LDS broadcast
        if (pack == 0) {                          // dead: write zeros, done
            if (lane < 3) kout[lane] = 0.0f;
            continue;
        }

        const int x1r = pack & 255;
        const int y1r = (pack >> 8) & 255;
        const int x2r = (pack >> 16) & 255;
        const int y2r = (pack >> 24) & 255;

        const float4* __restrict__ b4 =
            (const float4*)(hm + (size_t)(b * NK + k) * (NH * NW));   // 64KB-aligned

        const int xa     = x1r & ~3;                    // align ROI left edge down
        const int C4     = (x2r - xa + 3) >> 2;         // float4 chunks per row, 1..32
        const int R      = y2r - y1r;
        const int total4 = R * C4;                      // < 2^12
        const unsigned M = (C4 > 1) ? (0xFFFFFFFFu / (unsigned)C4 + 1u) : 0u;

        float best = -INFINITY;
        int   bidx = 0x7fffffff;                        // global flat idx y*NW+x

        auto proc = [&](int idx, float4 v) {
            const int row = (C4 == 1) ? idx : (int)__umulhi((unsigned)idx, M);
            const int xb  = xa + (idx - row * C4) * 4;
            const int g   = (y1r + row) * NW + xb;
            // component order = increasing x = increasing flat idx; strict > keeps
            // the earliest occurrence (argmax tie semantics)
            const float v0 = (xb + 0 >= x1r && xb + 0 < x2r) ? v.x : -INFINITY;
            const float v1 = (xb + 1 >= x1r && xb + 1 < x2r) ? v.y : -INFINITY;
            const float v2 = (xb + 2 >= x1r && xb + 2 < x2r) ? v.z : -INFINITY;
            const float v3 = (xb + 3 < x2r) ? v.w : -INFINITY;
            if (v0 > best) { best = v0; bidx = g + 0; }
            if (v1 > best) { best = v1; bidx = g + 1; }
            if (v2 > best) { best = v2; bidx = g + 2; }
            if (v3 > best) { best = v3; bidx = g + 3; }
        };
        auto caddr = [&](int idx) {
            const int row = (C4 == 1) ? idx : (int)__umulhi((unsigned)idx, M);
            return (y1r + row) * (NW / 4) + (xa >> 2) + (idx - row * C4);
        };

        int idx = lane;
        // 4 chunk-loads in flight per iteration (16 values).
        for (; idx + 192 < total4; idx += 256) {
            const int a0 = caddr(idx), a1 = caddr(idx + 64), a2 = caddr(idx + 128), a3 = caddr(idx + 192);
            const float4 v0 = b4[a0];
            const float4 v1 = b4[a1];
            const float4 v2 = b4[a2];
            const float4 v3 = b4[a3];
            proc(idx, v0);
            proc(idx + 64, v1);
            proc(idx + 128, v2);
            proc(idx + 192, v3);
        }
        for (; idx < total4; idx += 64) proc(idx, b4[caddr(idx)]);

        // 64-lane shuffle argmax reduce; tie -> smaller flat index (argmax semantics)
        for (int off = 32; off >= 1; off >>= 1) {
            const float ov = __shfl_down(best, off);
            const int   oi = __shfl_down(bidx, off);
            if (ov > best || (ov == best && oi < bidx)) { best = ov; bidx = oi; }
        }

        if (lane == 0) {
            const int col = bidx & (NW - 1);
            const int row = bidx >> 7;
            float conf = best;
            if (conf < KP_CONF) conf = 0.0f;
            kout[0] = (float)col / sxl;
            kout[1] = (float)row / syl;
            kout[2] = conf;
        }
    }
}

extern "C" void kernel_launch(void* const* d_in, const int* in_sizes, int n_in,
                              void* d_out, int out_size, void* d_ws, size_t ws_size,
                              hipStream_t stream) {
    const float* logits = (const float*)d_in[0];   // [4,100,2]
    const float* pboxes = (const float*)d_in[1];   // [4,100,4]
    const float* hm     = (const float*)d_in[2];   // [4,17,128,128]
    const int*   img_h  = (const int*)d_in[3];
    const int*   img_w  = (const int*)d_in[4];
    float* out = (float*)d_out;

    int* qpack = (int*)d_ws;                       // [400] ints

    nms_kernel<<<NB, 128, 0, stream>>>(logits, pboxes, img_h, img_w, out, qpack);
    scan_kernel<<<K2_BLOCKS, 128, 0, stream>>>(hm, qpack, img_h, img_w, out);
}